// Round 15
// baseline (178.550 us; speedup 1.0000x reference)
//
#include <hip/hip_runtime.h>
#include <hip/hip_bf16.h>

typedef __attribute__((ext_vector_type(8))) short short8_t;
typedef __attribute__((ext_vector_type(4))) float f32x4;
typedef __attribute__((ext_vector_type(16))) float f32x16;
using bf16 = __hip_bfloat16;

#define MFMA_BF16(A, B, C) __builtin_amdgcn_mfma_f32_16x16x32_bf16((A), (B), (C), 0, 0, 0)
#define MFMA32_BF16(A, B, C) __builtin_amdgcn_mfma_f32_32x32x16_bf16((A), (B), (C), 0, 0, 0)

#define GLD_LDS16(g, l)                                                        \
  __builtin_amdgcn_global_load_lds(                                           \
      (const __attribute__((address_space(1))) unsigned int*)(const void*)(g),\
      (__attribute__((address_space(3))) unsigned int*)(void*)(l), 16, 0, 0)

__device__ __forceinline__ float bits2f(short s) {
  union { unsigned int u; float f; } c;
  c.u = ((unsigned int)(unsigned short)s) << 16;
  return c.f;
}
__device__ __forceinline__ short f2bits(float f) {
  bf16 h = __float2bfloat16(f);
  return *reinterpret_cast<short*>(&h);
}
__device__ __forceinline__ unsigned pack2(float lo, float hi) {
  return ((unsigned)(unsigned short)f2bits(lo)) |
         (((unsigned)(unsigned short)f2bits(hi)) << 16);
}
__device__ __forceinline__ float exp2_(float x) {
#if __has_builtin(__builtin_amdgcn_exp2f)
  return __builtin_amdgcn_exp2f(x);
#else
  return exp2f(x);
#endif
}

// ---------------- one-shot fp32 -> bf16 convert for x | wq|wk|wv | wo ----------------
__global__ __launch_bounds__(256) void cvt_all(const float* __restrict__ x,
                                               const float* __restrict__ wq,
                                               const float* __restrict__ wk,
                                               const float* __restrict__ wv,
                                               const float* __restrict__ wo,
                                               short* __restrict__ xb,
                                               short* __restrict__ wqkvb,
                                               short* __restrict__ wob) {
  int i = (blockIdx.x * 256 + threadIdx.x) * 4;
  const float* src;
  short* dst;
  if (i < 8388608) {
    src = x + i; dst = xb + i;
  } else if (i < 14680064) {
    int j = i - 8388608;
    dst = wqkvb + j;
    if (j < 4194304) src = wq + j;
    else if (j < 5242880) src = wk + (j - 4194304);
    else src = wv + (j - 5242880);
  } else {
    int j = i - 14680064;
    src = wo + j; dst = wob + j;
  }
  float4 v = *reinterpret_cast<const float4*>(src);
  short4 o;
  o.x = f2bits(v.x); o.y = f2bits(v.y); o.z = f2bits(v.z); o.w = f2bits(v.w);
  *reinterpret_cast<short4*>(dst) = o;
}

// ---------------- 8-phase 256x256 GEMM (R12 ledger, fences removed) ----------------
// BM=BN=256, BK=64, 8 waves (2Mx4N), per-wave 128x64. 128 KiB LDS: 2 bufs x
// {A0,A1,B0,B1} 16KB half-tiles. 4 phases/K-tile = C-quadrants. LEDGER
// (HW-proven in R12): B regions last read ph1 -> stage B(t+2) in ph2; A
// regions last read ph2 -> stage A(t+2) in ph3; tile t+1 staged last iter;
// end-of-iter vmcnt(8)+barrier => t+1 landed. CHANGE vs R12: NO asm
// lgkmcnt(0), NO sched_barrier(0) -- ds_reads are compiler-visible loads, so
// the compiler emits fine-grained lgkmcnt itself and stays free to schedule
// (m141: sched_barrier(0) order-pinning cost ~2x; this was R12's 29% util).
// Reads are consumed before each phase's closing barrier -> ledger intact.
template <int STORE_BF16>
__global__ __launch_bounds__(512, 2) void gemm_8p(const short* __restrict__ A,
                                                  const short* __restrict__ Bt,
                                                  void* __restrict__ C,
                                                  int M, int N, int K, int NBN) {
  __shared__ __align__(16) short lds[2 * 32768];  // 128 KiB
  const int nwg = gridDim.x;
  const int cpx = nwg >> 3;
  const int wg = ((int)blockIdx.x & 7) * cpx + ((int)blockIdx.x >> 3);
  const int m0 = (wg / NBN) * 256, n0 = (wg % NBN) * 256;

  const int tid = threadIdx.x, w = tid >> 6, lane = tid & 63;
  const int wm = w >> 2, wn = w & 3;
  const int rr = lane & 15, g = lane >> 4;

  const int prow = tid >> 3;
  const int lg = (tid & 7) ^ (prow & 7);
  const size_t ro0 = (size_t)prow * K + lg * 8;
  const size_t ro1 = ro0 + (size_t)64 * K;
  const short* Ab = A + (size_t)m0 * K;
  const short* Bb = Bt + (size_t)n0 * K;
  const short* Ab1 = Ab + (size_t)128 * K;
  const short* Bb1 = Bb + (size_t)128 * K;
  const int wofs = tid * 16;

#define STG8(bp, tt, regbuf) do {                                              \
    const short* s_ = (bp) + (size_t)(tt) * 64;                                \
    char* d_ = (char*)lds + (regbuf) + wofs;                                   \
    GLD_LDS16(s_ + ro0, d_);                                                   \
    GLD_LDS16(s_ + ro1, d_ + 8192);                                            \
  } while (0)

  const int xg0 = ((g ^ (rr & 7)) << 4);
  const int xg1 = (((4 + g) ^ (rr & 7)) << 4);
  const int aregion = wm * 16384;
  const int bregion = 32768 + (wn >> 1) * 16384;
  const int arow0 = rr * 128;
  const int brow0 = ((wn & 1) * 64 + rr) * 128;

  f32x4 acc[8][4];
#pragma unroll
  for (int i2 = 0; i2 < 8; ++i2)
#pragma unroll
    for (int jj = 0; jj < 4; ++jj) acc[i2][jj] = (f32x4){0.f, 0.f, 0.f, 0.f};

  const int nt = K >> 6;

  STG8(Ab, 0, 0);
  STG8(Ab1, 0, 16384);
  STG8(Bb, 0, 32768);
  STG8(Bb1, 0, 49152);
  if (nt > 1) {
    STG8(Ab, 1, 65536);
    STG8(Ab1, 1, 65536 + 16384);
    STG8(Bb, 1, 65536 + 32768);
    STG8(Bb1, 1, 65536 + 49152);
    asm volatile("s_waitcnt vmcnt(8)" ::: "memory");
  } else {
    asm volatile("s_waitcnt vmcnt(0)" ::: "memory");
  }
  asm volatile("s_barrier" ::: "memory");

  short8_t aF[4][2], b0F[2][2], b1F[2][2];

  for (int t = 0; t < nt; ++t) {
    const int bb = (t & 1) << 16;
    const char* L = (const char*)lds;
    const bool st2 = (t + 2) < nt;

    // ===== phase 0: read aF(mh0) + b0F ; MFMA q(0,0) =====
#pragma unroll
    for (int mi = 0; mi < 4; ++mi) {
      int rb = bb + aregion + arow0 + mi * 2048;
      aF[mi][0] = *(const short8_t*)(L + rb + xg0);
      aF[mi][1] = *(const short8_t*)(L + rb + xg1);
    }
#pragma unroll
    for (int ni = 0; ni < 2; ++ni) {
      int rb = bb + bregion + brow0 + ni * 2048;
      b0F[ni][0] = *(const short8_t*)(L + rb + xg0);
      b0F[ni][1] = *(const short8_t*)(L + rb + xg1);
    }
    asm volatile("s_barrier" ::: "memory");
    __builtin_amdgcn_s_setprio(1);
#pragma unroll
    for (int kk = 0; kk < 2; ++kk)
#pragma unroll
      for (int mi = 0; mi < 4; ++mi)
#pragma unroll
        for (int ni = 0; ni < 2; ++ni)
          acc[mi][ni] = MFMA_BF16(aF[mi][kk], b0F[ni][kk], acc[mi][ni]);
    __builtin_amdgcn_s_setprio(0);
    asm volatile("s_barrier" ::: "memory");

    // ===== phase 1: read b1F ; MFMA q(0,1) =====
#pragma unroll
    for (int ni = 0; ni < 2; ++ni) {
      int rb = bb + bregion + brow0 + 4096 + ni * 2048;
      b1F[ni][0] = *(const short8_t*)(L + rb + xg0);
      b1F[ni][1] = *(const short8_t*)(L + rb + xg1);
    }
    asm volatile("s_barrier" ::: "memory");
    __builtin_amdgcn_s_setprio(1);
#pragma unroll
    for (int kk = 0; kk < 2; ++kk)
#pragma unroll
      for (int mi = 0; mi < 4; ++mi)
#pragma unroll
        for (int ni = 0; ni < 2; ++ni)
          acc[mi][2 + ni] = MFMA_BF16(aF[mi][kk], b1F[ni][kk], acc[mi][2 + ni]);
    __builtin_amdgcn_s_setprio(0);
    asm volatile("s_barrier" ::: "memory");

    // ===== phase 2: read aF(mh1) ; stage B0+B1(t+2) (B last read ph1) ; MFMA q(1,1) =====
#pragma unroll
    for (int mi = 0; mi < 4; ++mi) {
      int rb = bb + aregion + arow0 + 8192 + mi * 2048;
      aF[mi][0] = *(const short8_t*)(L + rb + xg0);
      aF[mi][1] = *(const short8_t*)(L + rb + xg1);
    }
    if (st2) {
      STG8(Bb, t + 2, bb + 32768);
      STG8(Bb1, t + 2, bb + 49152);
    }
    asm volatile("s_barrier" ::: "memory");
    __builtin_amdgcn_s_setprio(1);
#pragma unroll
    for (int kk = 0; kk < 2; ++kk)
#pragma unroll
      for (int mi = 0; mi < 4; ++mi)
#pragma unroll
        for (int ni = 0; ni < 2; ++ni)
          acc[4 + mi][2 + ni] = MFMA_BF16(aF[mi][kk], b1F[ni][kk], acc[4 + mi][2 + ni]);
    __builtin_amdgcn_s_setprio(0);
    asm volatile("s_barrier" ::: "memory");

    // ===== phase 3: stage A0+A1(t+2) (A last read ph2) ; MFMA q(1,0) ; vmcnt ; barrier =====
    if (st2) {
      STG8(Ab, t + 2, bb + 0);
      STG8(Ab1, t + 2, bb + 16384);
    }
    asm volatile("s_barrier" ::: "memory");
    __builtin_amdgcn_s_setprio(1);
#pragma unroll
    for (int kk = 0; kk < 2; ++kk)
#pragma unroll
      for (int mi = 0; mi < 4; ++mi)
#pragma unroll
        for (int ni = 0; ni < 2; ++ni)
          acc[4 + mi][ni] = MFMA_BF16(aF[mi][kk], b0F[ni][kk], acc[4 + mi][ni]);
    __builtin_amdgcn_s_setprio(0);
    if (st2)
      asm volatile("s_waitcnt vmcnt(8)" ::: "memory");  // t+1 landed; t+2 in flight
    else if (t + 1 < nt)
      asm volatile("s_waitcnt vmcnt(0)" ::: "memory");  // tail drain
    asm volatile("s_barrier" ::: "memory");
  }
#undef STG8

#pragma unroll
  for (int mh = 0; mh < 2; ++mh)
#pragma unroll
    for (int mi = 0; mi < 4; ++mi)
#pragma unroll
      for (int nh = 0; nh < 2; ++nh)
#pragma unroll
        for (int ni = 0; ni < 2; ++ni) {
          const int row = m0 + wm * 128 + mh * 64 + mi * 16 + g * 4;
          const int col = n0 + wn * 64 + nh * 32 + ni * 16 + rr;
          f32x4 v = acc[mh * 4 + mi][nh * 2 + ni];
#pragma unroll
          for (int j = 0; j < 4; ++j) {
            if (STORE_BF16)
              reinterpret_cast<short*>(C)[(size_t)(row + j) * N + col] = f2bits(v[j]);
            else
              reinterpret_cast<float*>(C)[(size_t)(row + j) * N + col] = v[j];
          }
        }
}

// ---------------- bf16 B^T GEMM v4 (proven) + 2D XCD chunking ----------------
template <int STORE_BF16>
__global__ __launch_bounds__(256, 2) void gemm_bt4(const short* __restrict__ A,
                                                   const short* __restrict__ Bt,
                                                   void* __restrict__ C,
                                                   int M, int N, int K,
                                                   int CM, int CN) {
  __shared__ __align__(16) short lds[2 * 16384];
  const int c = (int)blockIdx.x & 7;
  const int i = (int)blockIdx.x >> 3;
  const int cmi = c & 3, cni = c >> 2;
  const int m0 = (cmi * CM + (i % CM)) * 128;
  const int n0 = (cni * CN + (i / CM)) * 128;

  const int tid = threadIdx.x, w = tid >> 6, lane = tid & 63;
  const int wr = w >> 1, wc = w & 1;
  const int rr = lane & 15, g = lane >> 4;

  const int srow = tid >> 3;
  const int gc = (tid & 7) ^ (srow & 7);
  const short* Asrc = A + (size_t)(m0 + srow) * K + gc * 8;
  const short* Bsrc = Bt + (size_t)(n0 + srow) * K + gc * 8;
  const size_t rstep = (size_t)32 * K;
  const int dofs = tid * 16;

  const int abase = (((wr * 64 + rr) << 7) | (g << 4)) ^ ((rr & 7) << 4);
  const int bbase = ((((wc * 64 + rr) << 7) | (g << 4)) ^ ((rr & 7) << 4)) + 16384;

  f32x4 acc[4][4];
#pragma unroll
  for (int mi = 0; mi < 4; ++mi)
#pragma unroll
    for (int ni = 0; ni < 4; ++ni) acc[mi][ni] = (f32x4){0.f, 0.f, 0.f, 0.f};

  const int nt = K >> 6;

#define STAGE4(t, bufbyte) do {                                                \
    const short* a_ = Asrc + (size_t)(t) * 64;                                 \
    const short* b_ = Bsrc + (size_t)(t) * 64;                                 \
    char* la_ = (char*)lds + (bufbyte) + dofs;                                 \
    GLD_LDS16(a_,             la_);                                            \
    GLD_LDS16(a_ + rstep,     la_ + 4096);                                     \
    GLD_LDS16(a_ + 2 * rstep, la_ + 8192);                                     \
    GLD_LDS16(a_ + 3 * rstep, la_ + 12288);                                    \
    GLD_LDS16(b_,             la_ + 16384);                                    \
    GLD_LDS16(b_ + rstep,     la_ + 20480);                                    \
    GLD_LDS16(b_ + 2 * rstep, la_ + 24576);                                    \
    GLD_LDS16(b_ + 3 * rstep, la_ + 28672);                                    \
  } while (0)

  STAGE4(0, 0);
  asm volatile("s_waitcnt vmcnt(0)" ::: "memory");
  asm volatile("s_barrier" ::: "memory");

  int cur = 0;
  for (int t = 0; t < nt; ++t) {
    if (t + 1 < nt) STAGE4(t + 1, cur ^ 32768);
    const char* bufp = (const char*)lds + cur;
#pragma unroll
    for (int kk = 0; kk < 2; ++kk) {
      const int ko = kk * 64;
      short8_t a0 = *(const short8_t*)(bufp + ((abase ^ ko)));
      short8_t a1 = *(const short8_t*)(bufp + ((abase ^ ko) + 2048));
      short8_t a2 = *(const short8_t*)(bufp + ((abase ^ ko) + 4096));
      short8_t a3 = *(const short8_t*)(bufp + ((abase ^ ko) + 6144));
      short8_t b0 = *(const short8_t*)(bufp + ((bbase ^ ko)));
      short8_t b1 = *(const short8_t*)(bufp + ((bbase ^ ko) + 2048));
      short8_t b2 = *(const short8_t*)(bufp + ((bbase ^ ko) + 4096));
      short8_t b3 = *(const short8_t*)(bufp + ((bbase ^ ko) + 6144));
      __builtin_amdgcn_s_setprio(1);
      acc[0][0] = MFMA_BF16(a0, b0, acc[0][0]);
      acc[0][1] = MFMA_BF16(a0, b1, acc[0][1]);
      acc[0][2] = MFMA_BF16(a0, b2, acc[0][2]);
      acc[0][3] = MFMA_BF16(a0, b3, acc[0][3]);
      acc[1][0] = MFMA_BF16(a1, b0, acc[1][0]);
      acc[1][1] = MFMA_BF16(a1, b1, acc[1][1]);
      acc[1][2] = MFMA_BF16(a1, b2, acc[1][2]);
      acc[1][3] = MFMA_BF16(a1, b3, acc[1][3]);
      acc[2][0] = MFMA_BF16(a2, b0, acc[2][0]);
      acc[2][1] = MFMA_BF16(a2, b1, acc[2][1]);
      acc[2][2] = MFMA_BF16(a2, b2, acc[2][2]);
      acc[2][3] = MFMA_BF16(a2, b3, acc[2][3]);
      acc[3][0] = MFMA_BF16(a3, b0, acc[3][0]);
      acc[3][1] = MFMA_BF16(a3, b1, acc[3][1]);
      acc[3][2] = MFMA_BF16(a3, b2, acc[3][2]);
      acc[3][3] = MFMA_BF16(a3, b3, acc[3][3]);
      __builtin_amdgcn_s_setprio(0);
    }
    if (t + 1 < nt) {
      asm volatile("s_waitcnt vmcnt(0)" ::: "memory");
      asm volatile("s_barrier" ::: "memory");
    }
    cur ^= 32768;
  }
#undef STAGE4

#pragma unroll
  for (int mi = 0; mi < 4; ++mi)
#pragma unroll
    for (int ni = 0; ni < 4; ++ni) {
      const int row = m0 + wr * 64 + mi * 16 + g * 4;
      const int col = n0 + wc * 64 + ni * 16 + rr;
#pragma unroll
      for (int j = 0; j < 4; ++j) {
        float v = acc[mi][ni][j];
        if (STORE_BF16)
          reinterpret_cast<short*>(C)[(size_t)(row + j) * N + col] = f2bits(v);
        else
          reinterpret_cast<float*>(C)[(size_t)(row + j) * N + col] = v;
      }
    }
}

// ---------------- RoPE + RMS for q and k (4 units / 256-thread block) ----------------
__global__ __launch_bounds__(256) void rope_rms_qk(const short* __restrict__ qkv,
                                                   const float* __restrict__ cosT,
                                                   const float* __restrict__ sinT,
                                                   short* __restrict__ qO,
                                                   short* __restrict__ kO) {
  const int T = 2048;
  int unit = blockIdx.x * 4 + (threadIdx.x >> 6);
  int lane = threadIdx.x & 63;
  int hh = unit % 20;
  int t = (unit / 20) % T;
  int b = unit / (20 * T);
  int col = hh < 16 ? hh * 128 : 2048 + (hh - 16) * 128;
  const short* src = qkv + (size_t)(b * T + t) * 3072 + col;
  float t1 = bits2f(src[lane]), t2 = bits2f(src[lane + 64]);
  float c = cosT[t * 64 + lane], s = sinT[t * 64 + lane];
  float o1 = t1 * c + t2 * s;
  float o2 = t2 * c - t1 * s;
  float ss = o1 * o1 + o2 * o2;
#pragma unroll
  for (int o = 1; o < 64; o <<= 1) ss += __shfl_xor(ss, o, 64);
  float r = rsqrtf(ss * (1.f / 128.f) + 1.1920929e-07f);
  short* dst;
  if (hh < 16) {
    r *= 0.08838834764831845f * 1.4426950408889634f;  // 1/sqrt(128) * log2e
    dst = qO + ((size_t)(b * 16 + hh) * T + t) * 128;
  } else {
    dst = kO + ((size_t)(b * 4 + (hh - 16)) * T + t) * 128;
  }
  dst[lane] = f2bits(o1 * r);
  dst[lane + 64] = f2bits(o2 * r);
}

// ---------------- fused v-gate + transpose: qkv v-slice -> vT [bkv][d][t] ----------------
__global__ __launch_bounds__(256) void vgate_t(const short* __restrict__ qkv,
                                               const float* __restrict__ x,
                                               const float* __restrict__ ve,
                                               const float* __restrict__ wgate,
                                               short* __restrict__ vT) {
  const int T = 2048;
  int bkv = blockIdx.x & 7;
  int t0 = (blockIdx.x >> 3) * 64;
  int b = bkv >> 2, kv = bkv & 3;
  __shared__ __align__(16) short L[128 * 64];
  int tid = threadIdx.x;
  int tt = tid >> 2, q = tid & 3;
  size_t m = (size_t)b * T + t0 + tt;
  float z = 0.f;
  const float* xp = x + m * 2048 + q * 8;
  const float* wgp = wgate + kv * 32 + q * 8;
#pragma unroll
  for (int i = 0; i < 8; ++i) z += xp[i] * wgp[i];
  z += __shfl_xor(z, 1, 64);
  z += __shfl_xor(z, 2, 64);
  float gate = 2.f / (1.f + __expf(-z));
  const short* vsrc = qkv + m * 3072 + 2560 + kv * 128 + q * 32;
  const float* vesrc = ve + m * 512 + kv * 128 + q * 32;
  short8_t v0 = *(const short8_t*)(vsrc);
  short8_t v1 = *(const short8_t*)(vsrc + 8);
  short8_t v2 = *(const short8_t*)(vsrc + 16);
  short8_t v3 = *(const short8_t*)(vsrc + 24);
  float4 e[8];
#pragma unroll
  for (int i = 0; i < 8; ++i) e[i] = *(const float4*)(vesrc + i * 4);
#pragma unroll
  for (int i = 0; i < 32; ++i) {
    int d = q * 32 + i;
    short vv = i < 8 ? v0[i] : i < 16 ? v1[i - 8] : i < 24 ? v2[i - 16] : v3[i - 24];
    float ev = (&e[i >> 2].x)[i & 3];
    int byte = (d * 128 + tt * 2) ^ ((d & 7) << 4);
    *(short*)((char*)L + byte) = f2bits(bits2f(vv) + gate * ev);
  }
  __syncthreads();
  int d = tid >> 1, th = tid & 1;
  const char* Lp = (const char*)L;
#pragma unroll
  for (int g2 = 0; g2 < 4; ++g2) {
    short8_t o = *(const short8_t*)(Lp + ((d * 128 + th * 64 + g2 * 16) ^ ((d & 7) << 4)));
    *(short8_t*)(vT + ((size_t)bkv * 128 + d) * T + t0 + th * 32 + g2 * 8) = o;
  }
}

// ---------------- sliding-window flash attention v4: 4 GQA heads / block ----------------
__global__ __launch_bounds__(512) void attn_sw4(const short* __restrict__ Q,
                                                const short* __restrict__ K,
                                                const short* __restrict__ VT,
                                                short* __restrict__ Y,
                                                const int* __restrict__ winp) {
  const int T = 2048, H = 16;
  const int win = *winp;
  int combo = blockIdx.x & 7;          // (b,kvh) -> XCD pin
  int j = blockIdx.x >> 3;             // 0..31
  int b = combo >> 2, kvh = combo & 3;
  int q0 = (31 - j) * 64;              // heavy spans first

  __shared__ __align__(16) short Ks[2][64 * 128];
  __shared__ __align__(16) short Vs[2][128 * 64];

  int tid = threadIdx.x, w = tid >> 6, lane = tid & 63;
  int ql = lane & 31, hi = lane >> 5;
  int h = kvh * 4 + (w >> 1);
  int qrow = q0 + (w & 1) * 32 + ql;

  const short* qbase = Q + ((size_t)(b * H + h) * T + qrow) * 128;
  short8_t qf[8];
#pragma unroll
  for (int ks = 0; ks < 8; ++ks)
    qf[ks] = *reinterpret_cast<const short8_t*>(qbase + ks * 16 + hi * 8);

  const short* kbase = K + (size_t)(b * 4 + kvh) * T * 128;
  const short* vtbase = VT + (size_t)(b * 4 + kvh) * 128 * T;

  f32x16 acc[4];
#pragma unroll
  for (int dt = 0; dt < 4; ++dt)
#pragma unroll
    for (int r = 0; r < 16; ++r) acc[dt][r] = 0.f;
  float mreg = -1e30f, lsum = 0.f;

  int lo = q0 - win + 1;
  if (lo < 0) lo = 0;
  lo &= ~63;
  const int nt = (q0 + 64 - lo) >> 6;
  int qmin = q0 + (w & 1) * 32, qmax = qmin + 31;

#define STAGE_A(ti, bi) do {                                                   \
    int kc_ = lo + (ti) * 64;                                                  \
    _Pragma("unroll")                                                          \
    for (int r = 0; r < 2; ++r) {                                              \
      int seg = r * 8 + w;                                                     \
      int slot = seg * 64 + lane;                                              \
      int krow = slot >> 4;                                                    \
      int gc = (slot & 15) ^ (krow & 7);                                       \
      GLD_LDS16(kbase + (size_t)(kc_ + krow) * 128 + gc * 8,                   \
                (char*)Ks[bi] + seg * 1024);                                   \
    }                                                                          \
    _Pragma("unroll")                                                          \
    for (int r = 0; r < 2; ++r) {                                              \
      int seg = r * 8 + w;                                                     \
      int slot = seg * 64 + lane;                                              \
      int d_ = slot >> 3;                                                      \
      int gc = (slot & 7) ^ (d_ & 7);                                          \
      GLD_LDS16(vtbase + (size_t)d_ * T + kc_ + gc * 8,                        \
                (char*)Vs[bi] + seg * 1024);                                   \
    }                                                                          \
  } while (0)

  STAGE_A(0, 0);

  int cur = 0;
  for (int t = 0; t < nt; ++t) {
    if (t + 1 < nt) {
      STAGE_A(t + 1, cur ^ 1);
      asm volatile("s_waitcnt vmcnt(4)" ::: "memory");
    } else {
      asm volatile("s_waitcnt vmcnt(0)" ::: "memory");
    }
    asm volatile("s_barrier" ::: "memory");

    int kc = lo + t * 64;
    bool active = (kc <= qmax) && (kc + 63 >= qmin - win + 1);
    if (active) {
      const char* Kp = (const char*)Ks[cur];
      const char* Vp = (const char*)Vs[cur];
      f32x16 sA[2];
#pragma unroll
      for (int r = 0; r < 16; ++r) { sA[0][r] = 0.f; sA[1][r] = 0.f; }
#pragma unroll
      for (int kt = 0; kt < 2; ++kt) {
        int kr = kt * 32 + ql;
#pragma unroll
        for (int ks = 0; ks < 8; ++ks) {
          int byte = kr * 256 + (((ks * 2 + hi) ^ (kr & 7)) << 4);
          short8_t kf = *reinterpret_cast<const short8_t*>(Kp + byte);
          sA[kt] = MFMA32_BF16(kf, qf[ks], sA[kt]);
        }
      }
      float pmax = -1e30f;
#pragma unroll
      for (int kt = 0; kt < 2; ++kt)
#pragma unroll
        for (int r = 0; r < 16; ++r) {
          int key = kc + kt * 32 + (r & 3) + 8 * (r >> 2) + 4 * hi;
          float sv = sA[kt][r];
          sv = ((unsigned)(qrow - key) < (unsigned)win) ? sv : -1e30f;
          sA[kt][r] = sv;
          pmax = fmaxf(pmax, sv);
        }
      pmax = fmaxf(pmax, __shfl_xor(pmax, 32, 64));
      float mn = fmaxf(mreg, pmax);
      float corr = exp2_(mreg - mn);
      mreg = mn;
      float rs = 0.f;
#pragma unroll
      for (int kt = 0; kt < 2; ++kt)
#pragma unroll
        for (int r = 0; r < 16; ++r) {
          float p = exp2_(sA[kt][r] - mn);
          sA[kt][r] = p;
          rs += p;
        }
      rs += __shfl_xor(rs, 32, 64);
      lsum = lsum * corr + rs;
#pragma unroll
      for (int dt = 0; dt < 4; ++dt)
#pragma unroll
        for (int r = 0; r < 16; ++r) acc[dt][r] *= corr;

#pragma unroll
      for (int kt = 0; kt < 2; ++kt)
#pragma unroll
        for (int s = 0; s < 2; ++s) {
          unsigned a = pack2(sA[kt][8 * s + 0], sA[kt][8 * s + 1]);
          unsigned bb = pack2(sA[kt][8 * s + 2], sA[kt][8 * s + 3]);
          unsigned c = pack2(sA[kt][8 * s + 4], sA[kt][8 * s + 5]);
          unsigned dd = pack2(sA[kt][8 * s + 6], sA[kt][8 * s + 7]);
          unsigned sa = __shfl_xor(a, 32, 64);
          unsigned sb = __shfl_xor(bb, 32, 64);
          unsigned sc2 = __shfl_xor(c, 32, 64);
          unsigned sd = __shfl_xor(dd, 32, 64);
          union { unsigned u[4]; short8_t s8; } pu;
          pu.u[0] = hi ? sc2 : a;
          pu.u[1] = hi ? sd : bb;
          pu.u[2] = hi ? c : sa;
          pu.u[3] = hi ? dd : sb;
          const int kst = kt * 2 + s;
#pragma unroll
          for (int dt = 0; dt < 4; ++dt) {
            int d_ = dt * 32 + ql;
            int byte = (d_ << 7) + ((((kst * 2 + hi)) ^ (d_ & 7)) << 4);
            short8_t vf = *reinterpret_cast<const short8_t*>(Vp + byte);
            acc[dt] = MFMA32_BF16(vf, pu.s8, acc[dt]);
          }
        }
    }
    asm volatile("s_barrier" ::: "memory");
    cur ^= 1;
  }
#undef STAGE_A

  float rinv = 1.f / lsum;
  short* ybase = Y + ((size_t)(b * T + qrow) * H + h) * 128;
#pragma unroll
  for (int dt = 0; dt < 4; ++dt)
#pragma unroll
    for (int g2 = 0; g2 < 4; ++g2) {
      short4 o;
      o.x = f2bits(acc[dt][g2 * 4 + 0] * rinv);
      o.y = f2bits(acc[dt][g2 * 4 + 1] * rinv);
      o.z = f2bits(acc[dt][g2 * 4 + 2] * rinv);
      o.w = f2bits(acc[dt][g2 * 4 + 3] * rinv);
      *reinterpret_cast<short4*>(ybase + dt * 32 + 8 * g2 + 4 * hi) = o;
    }
}

// ---------------- launcher ----------------
extern "C" void kernel_launch(void* const* d_in, const int* in_sizes, int n_in,
                              void* d_out, int out_size, void* d_ws, size_t ws_size,
                              hipStream_t stream) {
  const float* x = (const float*)d_in[0];
  const float* ve = (const float*)d_in[1];
  const float* cosT = (const float*)d_in[2];
  const float* sinT = (const float*)d_in[3];
  const float* wq = (const float*)d_in[4];
  const float* wk = (const float*)d_in[5];
  const float* wv = (const float*)d_in[6];
  const float* wo = (const float*)d_in[7];
  const float* wgate = (const float*)d_in[8];
  const int* winp = (const int*)d_in[9];
  float* out = (float*)d_out;
  char* ws = (char*)d_ws;

  const int B = 2, T = 2048;
  short* xb    = (short*)(ws);
  short* wqkvb = (short*)(ws + 16777216);
  short* wob   = (short*)(ws + 29360128);
  short* qkv   = (short*)(ws + 37748736);
  short* qpost = (short*)(ws + 62914560);
  short* kpost = (short*)(ws + 79691776);
  short* vTb   = (short*)(ws + 83886080);
  short* ybuf  = (short*)(ws + 88080384);

  cvt_all<<<dim3(18432), 256, 0, stream>>>(x, wq, wk, wv, wo, xb, wqkvb, wob);

  // QKV: M=4096 N=3072 K=2048 -> 16x12 = 192 blocks (8-phase 256^2, %8==0)
  gemm_8p<1><<<dim3(192), 512, 0, stream>>>(xb, wqkvb, qkv, 4096, 3072, 2048, 12);

  rope_rms_qk<<<dim3(B * T * 20 / 4), 256, 0, stream>>>(qkv, cosT, sinT, qpost, kpost);
  vgate_t<<<dim3(8 * (T / 64)), 256, 0, stream>>>(qkv, x, ve, wgate, vTb);

  // attention: 256 blocks = (b,kvh) x 32 q-spans, 8 waves (4 heads / block)
  attn_sw4<<<dim3(256), 512, 0, stream>>>(qpost, kpost, vTb, ybuf, winp);

  // out-proj: M=4096 N=2048 K=2048; grid 512 = 8 chunks x (CM=8 x CN=8)
  gemm_bt4<0><<<dim3(512), 256, 0, stream>>>(ybuf, wob, out, 4096, 2048, 2048, 8, 8);
}

// Round 16
// 159.012 us; speedup vs baseline: 1.1229x; 1.1229x over previous
//
#include <hip/hip_runtime.h>
#include <hip/hip_bf16.h>

typedef __attribute__((ext_vector_type(8))) short short8_t;
typedef __attribute__((ext_vector_type(4))) float f32x4;
typedef __attribute__((ext_vector_type(16))) float f32x16;
using bf16 = __hip_bfloat16;

#define MFMA_BF16(A, B, C) __builtin_amdgcn_mfma_f32_16x16x32_bf16((A), (B), (C), 0, 0, 0)
#define MFMA32_BF16(A, B, C) __builtin_amdgcn_mfma_f32_32x32x16_bf16((A), (B), (C), 0, 0, 0)

#define GLD_LDS16(g, l)                                                        \
  __builtin_amdgcn_global_load_lds(                                           \
      (const __attribute__((address_space(1))) unsigned int*)(const void*)(g),\
      (__attribute__((address_space(3))) unsigned int*)(void*)(l), 16, 0, 0)

__device__ __forceinline__ float bits2f(short s) {
  union { unsigned int u; float f; } c;
  c.u = ((unsigned int)(unsigned short)s) << 16;
  return c.f;
}
__device__ __forceinline__ short f2bits(float f) {
  bf16 h = __float2bfloat16(f);
  return *reinterpret_cast<short*>(&h);
}
__device__ __forceinline__ unsigned pack2(float lo, float hi) {
  return ((unsigned)(unsigned short)f2bits(lo)) |
         (((unsigned)(unsigned short)f2bits(hi)) << 16);
}
__device__ __forceinline__ float exp2_(float x) {
#if __has_builtin(__builtin_amdgcn_exp2f)
  return __builtin_amdgcn_exp2f(x);
#else
  return exp2f(x);
#endif
}

// ---------------- one-shot fp32 -> bf16 convert for x | wq|wk|wv | wo ----------------
__global__ __launch_bounds__(256) void cvt_all(const float* __restrict__ x,
                                               const float* __restrict__ wq,
                                               const float* __restrict__ wk,
                                               const float* __restrict__ wv,
                                               const float* __restrict__ wo,
                                               short* __restrict__ xb,
                                               short* __restrict__ wqkvb,
                                               short* __restrict__ wob) {
  int i = (blockIdx.x * 256 + threadIdx.x) * 4;
  const float* src;
  short* dst;
  if (i < 8388608) {
    src = x + i; dst = xb + i;
  } else if (i < 14680064) {
    int j = i - 8388608;
    dst = wqkvb + j;
    if (j < 4194304) src = wq + j;
    else if (j < 5242880) src = wk + (j - 4194304);
    else src = wv + (j - 5242880);
  } else {
    int j = i - 14680064;
    src = wo + j; dst = wob + j;
  }
  float4 v = *reinterpret_cast<const float4*>(src);
  short4 o;
  o.x = f2bits(v.x); o.y = f2bits(v.y); o.z = f2bits(v.z); o.w = f2bits(v.w);
  *reinterpret_cast<short4*>(dst) = o;
}

// ---------------- bf16 B^T GEMM v4 + 2D XCD chunking + fused epilogue ----------------
// (R14 final) FUSED=1 (QKV): B-frag cols remapped per wave to (ni>>1)*64 +
// wc*32 + (ni&1)*16 + rr, so each lane holds (d, d+64) pairs of the same token
// row -> rope is register-local. RMS = 16-lane shfl_xor + 1KB cross-wave LDS
// partial. v-slot: gate+ve+transpose via 32KB LDS. FUSED=0 (wo): original
// mapping, plain fp32 C store.
template <int STORE_BF16, int FUSED>
__global__ __launch_bounds__(256, 2) void gemm_bt4(
    const short* __restrict__ A, const short* __restrict__ Bt,
    void* __restrict__ C, int M, int N, int K, int CM, int CN,
    short* __restrict__ qO, short* __restrict__ kO, short* __restrict__ vTO,
    const float* __restrict__ cosT, const float* __restrict__ sinT,
    const float* __restrict__ x32, const float* __restrict__ ve32,
    const float* __restrict__ wg32) {
  __shared__ __align__(16) char smem[65536];
  short* lds = (short*)smem;
  const int c = (int)blockIdx.x & 7;
  const int i = (int)blockIdx.x >> 3;
  const int cmi = c & 3, cni = c >> 2;
  const int m0 = (cmi * CM + (i % CM)) * 128;
  const int n0 = (cni * CN + (i / CM)) * 128;

  const int tid = threadIdx.x, w = tid >> 6, lane = tid & 63;
  const int wr = w >> 1, wc = w & 1;
  const int rr = lane & 15, g = lane >> 4;

  const int srow = tid >> 3;
  const int gc = (tid & 7) ^ (srow & 7);
  const short* Asrc = A + (size_t)(m0 + srow) * K + gc * 8;
  const short* Bsrc = Bt + (size_t)(n0 + srow) * K + gc * 8;
  const size_t rstep = (size_t)32 * K;
  const int dofs = tid * 16;

  const int abase = (((wr * 64 + rr) << 7) | (g << 4)) ^ ((rr & 7) << 4);
  const int brow = (FUSED ? wc * 32 : wc * 64) + rr;
  const int bbase = (((brow << 7) | (g << 4)) ^ ((rr & 7) << 4)) + 16384;
  const int BO1 = 2048;                      // +16 rows
  const int BO2 = FUSED ? 8192 : 4096;       // +64 / +32 rows
  const int BO3 = FUSED ? 10240 : 6144;      // +80 / +48 rows

  f32x4 acc[4][4];
#pragma unroll
  for (int mi = 0; mi < 4; ++mi)
#pragma unroll
    for (int ni = 0; ni < 4; ++ni) acc[mi][ni] = (f32x4){0.f, 0.f, 0.f, 0.f};

  const int nt = K >> 6;

#define STAGE4(t, bufbyte) do {                                                \
    const short* a_ = Asrc + (size_t)(t) * 64;                                 \
    const short* b_ = Bsrc + (size_t)(t) * 64;                                 \
    char* la_ = (char*)lds + (bufbyte) + dofs;                                 \
    GLD_LDS16(a_,             la_);                                            \
    GLD_LDS16(a_ + rstep,     la_ + 4096);                                     \
    GLD_LDS16(a_ + 2 * rstep, la_ + 8192);                                     \
    GLD_LDS16(a_ + 3 * rstep, la_ + 12288);                                    \
    GLD_LDS16(b_,             la_ + 16384);                                    \
    GLD_LDS16(b_ + rstep,     la_ + 20480);                                    \
    GLD_LDS16(b_ + 2 * rstep, la_ + 24576);                                    \
    GLD_LDS16(b_ + 3 * rstep, la_ + 28672);                                    \
  } while (0)

  STAGE4(0, 0);
  asm volatile("s_waitcnt vmcnt(0)" ::: "memory");
  asm volatile("s_barrier" ::: "memory");

  int cur = 0;
  for (int t = 0; t < nt; ++t) {
    if (t + 1 < nt) STAGE4(t + 1, cur ^ 32768);
    const char* bufp = (const char*)lds + cur;
#pragma unroll
    for (int kk = 0; kk < 2; ++kk) {
      const int ko = kk * 64;
      short8_t a0 = *(const short8_t*)(bufp + ((abase ^ ko)));
      short8_t a1 = *(const short8_t*)(bufp + ((abase ^ ko) + 2048));
      short8_t a2 = *(const short8_t*)(bufp + ((abase ^ ko) + 4096));
      short8_t a3 = *(const short8_t*)(bufp + ((abase ^ ko) + 6144));
      short8_t b0 = *(const short8_t*)(bufp + ((bbase ^ ko)));
      short8_t b1 = *(const short8_t*)(bufp + ((bbase ^ ko) + BO1));
      short8_t b2 = *(const short8_t*)(bufp + ((bbase ^ ko) + BO2));
      short8_t b3 = *(const short8_t*)(bufp + ((bbase ^ ko) + BO3));
      __builtin_amdgcn_s_setprio(1);
      acc[0][0] = MFMA_BF16(a0, b0, acc[0][0]);
      acc[0][1] = MFMA_BF16(a0, b1, acc[0][1]);
      acc[0][2] = MFMA_BF16(a0, b2, acc[0][2]);
      acc[0][3] = MFMA_BF16(a0, b3, acc[0][3]);
      acc[1][0] = MFMA_BF16(a1, b0, acc[1][0]);
      acc[1][1] = MFMA_BF16(a1, b1, acc[1][1]);
      acc[1][2] = MFMA_BF16(a1, b2, acc[1][2]);
      acc[1][3] = MFMA_BF16(a1, b3, acc[1][3]);
      acc[2][0] = MFMA_BF16(a2, b0, acc[2][0]);
      acc[2][1] = MFMA_BF16(a2, b1, acc[2][1]);
      acc[2][2] = MFMA_BF16(a2, b2, acc[2][2]);
      acc[2][3] = MFMA_BF16(a2, b3, acc[2][3]);
      acc[3][0] = MFMA_BF16(a3, b0, acc[3][0]);
      acc[3][1] = MFMA_BF16(a3, b1, acc[3][1]);
      acc[3][2] = MFMA_BF16(a3, b2, acc[3][2]);
      acc[3][3] = MFMA_BF16(a3, b3, acc[3][3]);
      __builtin_amdgcn_s_setprio(0);
    }
    if (t + 1 < nt) {
      asm volatile("s_waitcnt vmcnt(0)" ::: "memory");
      asm volatile("s_barrier" ::: "memory");
    }
    cur ^= 32768;
  }
#undef STAGE4

  if (!FUSED) {
#pragma unroll
    for (int mi = 0; mi < 4; ++mi)
#pragma unroll
      for (int ni = 0; ni < 4; ++ni) {
        const int row = m0 + wr * 64 + mi * 16 + g * 4;
        const int col = n0 + wc * 64 + ni * 16 + rr;
#pragma unroll
        for (int j = 0; j < 4; ++j) {
          float v = acc[mi][ni][j];
          if (STORE_BF16)
            reinterpret_cast<short*>(C)[(size_t)(row + j) * N + col] = f2bits(v);
          else
            reinterpret_cast<float*>(C)[(size_t)(row + j) * N + col] = v;
        }
      }
    return;
  }

  // ================= fused epilogue =================
  __syncthreads();  // all LDS reads of the K-loop done before reuse
  const int slot = n0 >> 7;

  if (slot < 20) {
    // ---- q/k: register-local rope (d, d+64 in same lane) + cross-wave RMS ----
    const bool isq = slot < 16;
    const int colL = wc * 32 + rr;
    float o1v[4][2][4], o2v[4][2][4], ssp[4][4];
#pragma unroll
    for (int mi = 0; mi < 4; ++mi)
#pragma unroll
      for (int j = 0; j < 4; ++j) {
        int rw = wr * 64 + mi * 16 + g * 4 + j;
        int tk = (m0 + rw) & 2047;
        float ss = 0.f;
#pragma unroll
        for (int ni = 0; ni < 2; ++ni) {
          int cl = colL + ni * 16;
          float cv = cosT[tk * 64 + cl];
          float sv = sinT[tk * 64 + cl];
          float lo = acc[mi][ni][j], hi = acc[mi][ni + 2][j];
          float a = lo * cv + hi * sv;
          float b2 = hi * cv - lo * sv;
          o1v[mi][ni][j] = a;
          o2v[mi][ni][j] = b2;
          ss += a * a + b2 * b2;
        }
        ssp[mi][j] = ss;
      }
#pragma unroll
    for (int mi = 0; mi < 4; ++mi)
#pragma unroll
      for (int j = 0; j < 4; ++j) {
#pragma unroll
        for (int off = 1; off < 16; off <<= 1)
          ssp[mi][j] += __shfl_xor(ssp[mi][j], off, 64);
      }
    float* P = (float*)smem;  // [128][2] partial row-sums
    if (rr == 0) {
#pragma unroll
      for (int mi = 0; mi < 4; ++mi)
#pragma unroll
        for (int j = 0; j < 4; ++j) {
          int rw = wr * 64 + mi * 16 + g * 4 + j;
          P[rw * 2 + wc] = ssp[mi][j];
        }
    }
    __syncthreads();
    const float qs = 0.08838834764831845f * 1.4426950408889634f;  // 1/sqrt(128)*log2e
#pragma unroll
    for (int mi = 0; mi < 4; ++mi)
#pragma unroll
      for (int j = 0; j < 4; ++j) {
        int rw = wr * 64 + mi * 16 + g * 4 + j;
        int mglob = m0 + rw;
        int bb = mglob >> 11, tk = mglob & 2047;
        float sst = P[rw * 2] + P[rw * 2 + 1];
        float r = rsqrtf(sst * (1.f / 128.f) + 1.1920929e-07f);
        short* dst;
        if (isq) {
          r *= qs;
          dst = qO + ((size_t)(bb * 16 + slot) * 2048 + tk) * 128;
        } else {
          dst = kO + ((size_t)(bb * 4 + (slot - 16)) * 2048 + tk) * 128;
        }
#pragma unroll
        for (int ni = 0; ni < 2; ++ni) {
          int cl = colL + ni * 16;
          dst[cl] = f2bits(o1v[mi][ni][j] * r);
          dst[cl + 64] = f2bits(o2v[mi][ni][j] * r);
        }
      }
  } else {
    // ---- v: gate + ve, transpose to vT[d][t] ----
    const int kv = slot - 20;
    short* TL = (short*)smem;                    // [128 d][128 t] swizzled
    float* GL = (float*)(smem + 32768);          // 128 gates
    {
      int row = tid >> 1, u = tid & 1;
      size_t mglob = (size_t)(m0 + row);
      const float* xp = x32 + mglob * 2048 + u * 16;
      const float* wg = wg32 + kv * 32 + u * 16;
      float z = 0.f;
#pragma unroll
      for (int ii = 0; ii < 16; ++ii) z += xp[ii] * wg[ii];
      z += __shfl_xor(z, 1, 64);
      if (!u) GL[row] = 2.f / (1.f + __expf(-z));
    }
    __syncthreads();
#pragma unroll
    for (int mi = 0; mi < 4; ++mi)
#pragma unroll
      for (int ni = 0; ni < 4; ++ni) {
        int r0 = wr * 64 + mi * 16 + g * 4;
        int cl = (ni >> 1) * 64 + wc * 32 + (ni & 1) * 16 + rr;  // FUSED col map
#pragma unroll
        for (int j = 0; j < 4; ++j) {
          int rw = r0 + j;
          float gate = GL[rw];
          float ev = ve32[(size_t)(m0 + rw) * 512 + kv * 128 + cl];
          float v = acc[mi][ni][j] + gate * ev;
          int byte = ((cl << 8) + (rw << 1)) ^ ((cl & 7) << 4);
          *(short*)((char*)TL + byte) = f2bits(v);
        }
      }
    __syncthreads();
    int d = tid >> 1, th = tid & 1;
    int bb = m0 >> 11, t0l = m0 & 2047;
    short* vdst = vTO + ((size_t)(bb * 4 + kv) * 128 + d) * 2048 + t0l + th * 64;
    const char* TLp = (const char*)TL;
#pragma unroll
    for (int g2 = 0; g2 < 8; ++g2) {
      short8_t o = *(const short8_t*)(TLp + (((d << 8) + th * 128 + g2 * 16) ^ ((d & 7) << 4)));
      *(short8_t*)(vdst + g2 * 8) = o;
    }
  }
}

// ---------------- sliding-window flash attention v4: 4 GQA heads / block ----------------
__global__ __launch_bounds__(512) void attn_sw4(const short* __restrict__ Q,
                                                const short* __restrict__ K,
                                                const short* __restrict__ VT,
                                                short* __restrict__ Y,
                                                const int* __restrict__ winp) {
  const int T = 2048, H = 16;
  const int win = *winp;
  int combo = blockIdx.x & 7;          // (b,kvh) -> XCD pin
  int j = blockIdx.x >> 3;             // 0..31
  int b = combo >> 2, kvh = combo & 3;
  int q0 = (31 - j) * 64;              // heavy spans first

  __shared__ __align__(16) short Ks[2][64 * 128];
  __shared__ __align__(16) short Vs[2][128 * 64];

  int tid = threadIdx.x, w = tid >> 6, lane = tid & 63;
  int ql = lane & 31, hi = lane >> 5;
  int h = kvh * 4 + (w >> 1);
  int qrow = q0 + (w & 1) * 32 + ql;

  const short* qbase = Q + ((size_t)(b * H + h) * T + qrow) * 128;
  short8_t qf[8];
#pragma unroll
  for (int ks = 0; ks < 8; ++ks)
    qf[ks] = *reinterpret_cast<const short8_t*>(qbase + ks * 16 + hi * 8);

  const short* kbase = K + (size_t)(b * 4 + kvh) * T * 128;
  const short* vtbase = VT + (size_t)(b * 4 + kvh) * 128 * T;

  f32x16 acc[4];
#pragma unroll
  for (int dt = 0; dt < 4; ++dt)
#pragma unroll
    for (int r = 0; r < 16; ++r) acc[dt][r] = 0.f;
  float mreg = -1e30f, lsum = 0.f;

  int lo = q0 - win + 1;
  if (lo < 0) lo = 0;
  lo &= ~63;
  const int nt = (q0 + 64 - lo) >> 6;
  int qmin = q0 + (w & 1) * 32, qmax = qmin + 31;

#define STAGE_A(ti, bi) do {                                                   \
    int kc_ = lo + (ti) * 64;                                                  \
    _Pragma("unroll")                                                          \
    for (int r = 0; r < 2; ++r) {                                              \
      int seg = r * 8 + w;                                                     \
      int slot = seg * 64 + lane;                                              \
      int krow = slot >> 4;                                                    \
      int gc = (slot & 15) ^ (krow & 7);                                       \
      GLD_LDS16(kbase + (size_t)(kc_ + krow) * 128 + gc * 8,                   \
                (char*)Ks[bi] + seg * 1024);                                   \
    }                                                                          \
    _Pragma("unroll")                                                          \
    for (int r = 0; r < 2; ++r) {                                              \
      int seg = r * 8 + w;                                                     \
      int slot = seg * 64 + lane;                                              \
      int d_ = slot >> 3;                                                      \
      int gc = (slot & 7) ^ (d_ & 7);                                          \
      GLD_LDS16(vtbase + (size_t)d_ * T + kc_ + gc * 8,                        \
                (char*)Vs[bi] + seg * 1024);                                   \
    }                                                                          \
  } while (0)

  STAGE_A(0, 0);

  int cur = 0;
  for (int t = 0; t < nt; ++t) {
    if (t + 1 < nt) {
      STAGE_A(t + 1, cur ^ 1);
      asm volatile("s_waitcnt vmcnt(4)" ::: "memory");
    } else {
      asm volatile("s_waitcnt vmcnt(0)" ::: "memory");
    }
    asm volatile("s_barrier" ::: "memory");

    int kc = lo + t * 64;
    bool active = (kc <= qmax) && (kc + 63 >= qmin - win + 1);
    if (active) {
      const char* Kp = (const char*)Ks[cur];
      const char* Vp = (const char*)Vs[cur];
      f32x16 sA[2];
#pragma unroll
      for (int r = 0; r < 16; ++r) { sA[0][r] = 0.f; sA[1][r] = 0.f; }
#pragma unroll
      for (int kt = 0; kt < 2; ++kt) {
        int kr = kt * 32 + ql;
#pragma unroll
        for (int ks = 0; ks < 8; ++ks) {
          int byte = kr * 256 + (((ks * 2 + hi) ^ (kr & 7)) << 4);
          short8_t kf = *reinterpret_cast<const short8_t*>(Kp + byte);
          sA[kt] = MFMA32_BF16(kf, qf[ks], sA[kt]);
        }
      }
      float pmax = -1e30f;
#pragma unroll
      for (int kt = 0; kt < 2; ++kt)
#pragma unroll
        for (int r = 0; r < 16; ++r) {
          int key = kc + kt * 32 + (r & 3) + 8 * (r >> 2) + 4 * hi;
          float sv = sA[kt][r];
          sv = ((unsigned)(qrow - key) < (unsigned)win) ? sv : -1e30f;
          sA[kt][r] = sv;
          pmax = fmaxf(pmax, sv);
        }
      pmax = fmaxf(pmax, __shfl_xor(pmax, 32, 64));
      float mn = fmaxf(mreg, pmax);
      float corr = exp2_(mreg - mn);
      mreg = mn;
      float rs = 0.f;
#pragma unroll
      for (int kt = 0; kt < 2; ++kt)
#pragma unroll
        for (int r = 0; r < 16; ++r) {
          float p = exp2_(sA[kt][r] - mn);
          sA[kt][r] = p;
          rs += p;
        }
      rs += __shfl_xor(rs, 32, 64);
      lsum = lsum * corr + rs;
#pragma unroll
      for (int dt = 0; dt < 4; ++dt)
#pragma unroll
        for (int r = 0; r < 16; ++r) acc[dt][r] *= corr;

#pragma unroll
      for (int kt = 0; kt < 2; ++kt)
#pragma unroll
        for (int s = 0; s < 2; ++s) {
          unsigned a = pack2(sA[kt][8 * s + 0], sA[kt][8 * s + 1]);
          unsigned bb = pack2(sA[kt][8 * s + 2], sA[kt][8 * s + 3]);
          unsigned c = pack2(sA[kt][8 * s + 4], sA[kt][8 * s + 5]);
          unsigned dd = pack2(sA[kt][8 * s + 6], sA[kt][8 * s + 7]);
          unsigned sa = __shfl_xor(a, 32, 64);
          unsigned sb = __shfl_xor(bb, 32, 64);
          unsigned sc2 = __shfl_xor(c, 32, 64);
          unsigned sd = __shfl_xor(dd, 32, 64);
          union { unsigned u[4]; short8_t s8; } pu;
          pu.u[0] = hi ? sc2 : a;
          pu.u[1] = hi ? sd : bb;
          pu.u[2] = hi ? c : sa;
          pu.u[3] = hi ? dd : sb;
          const int kst = kt * 2 + s;
#pragma unroll
          for (int dt = 0; dt < 4; ++dt) {
            int d_ = dt * 32 + ql;
            int byte = (d_ << 7) + ((((kst * 2 + hi)) ^ (d_ & 7)) << 4);
            short8_t vf = *reinterpret_cast<const short8_t*>(Vp + byte);
            acc[dt] = MFMA32_BF16(vf, pu.s8, acc[dt]);
          }
        }
    }
    asm volatile("s_barrier" ::: "memory");
    cur ^= 1;
  }
#undef STAGE_A

  float rinv = 1.f / lsum;
  short* ybase = Y + ((size_t)(b * T + qrow) * H + h) * 128;
#pragma unroll
  for (int dt = 0; dt < 4; ++dt)
#pragma unroll
    for (int g2 = 0; g2 < 4; ++g2) {
      short4 o;
      o.x = f2bits(acc[dt][g2 * 4 + 0] * rinv);
      o.y = f2bits(acc[dt][g2 * 4 + 1] * rinv);
      o.z = f2bits(acc[dt][g2 * 4 + 2] * rinv);
      o.w = f2bits(acc[dt][g2 * 4 + 3] * rinv);
      *reinterpret_cast<short4*>(ybase + dt * 32 + 8 * g2 + 4 * hi) = o;
    }
}

// ---------------- launcher ----------------
extern "C" void kernel_launch(void* const* d_in, const int* in_sizes, int n_in,
                              void* d_out, int out_size, void* d_ws, size_t ws_size,
                              hipStream_t stream) {
  const float* x = (const float*)d_in[0];
  const float* ve = (const float*)d_in[1];
  const float* cosT = (const float*)d_in[2];
  const float* sinT = (const float*)d_in[3];
  const float* wq = (const float*)d_in[4];
  const float* wk = (const float*)d_in[5];
  const float* wv = (const float*)d_in[6];
  const float* wo = (const float*)d_in[7];
  const float* wgate = (const float*)d_in[8];
  const int* winp = (const int*)d_in[9];
  float* out = (float*)d_out;
  char* ws = (char*)d_ws;

  short* xb    = (short*)(ws);
  short* wqkvb = (short*)(ws + 16777216);
  short* wob   = (short*)(ws + 29360128);
  short* qpost = (short*)(ws + 62914560);
  short* kpost = (short*)(ws + 79691776);
  short* vTb   = (short*)(ws + 83886080);
  short* ybuf  = (short*)(ws + 88080384);

  cvt_all<<<dim3(18432), 256, 0, stream>>>(x, wq, wk, wv, wo, xb, wqkvb, wob);

  // QKV fused: M=4096 N=3072 K=2048; grid 768 = 8 chunks x (CM=8 x CN=12)
  gemm_bt4<1, 1><<<dim3(768), 256, 0, stream>>>(
      xb, wqkvb, nullptr, 4096, 3072, 2048, 8, 12,
      qpost, kpost, vTb, cosT, sinT, x, ve, wgate);

  // attention: 256 blocks = (b,kvh) x 32 q-spans, 8 waves (4 heads / block)
  attn_sw4<<<dim3(256), 512, 0, stream>>>(qpost, kpost, vTb, ybuf, winp);

  // out-proj: M=4096 N=2048 K=2048; grid 512 = 8 chunks x (CM=8 x CN=8)
  gemm_bt4<0, 0><<<dim3(512), 256, 0, stream>>>(
      ybuf, wob, out, 4096, 2048, 2048, 8, 8,
      nullptr, nullptr, nullptr, nullptr, nullptr, nullptr, nullptr, nullptr);
}